// Round 13
// baseline (478.805 us; speedup 1.0000x reference)
//
#include <hip/hip_runtime.h>
#include <math.h>

#define B_      2
#define S_      2048
#define HIDDEN_ 2048
#define HEADS_  16
#define QLORA_  1024
#define KVLORA_ 512
#define NOPE_   128
#define ROPE_   64
#define QHEAD_  192
#define VHEAD_  128

typedef __attribute__((ext_vector_type(8))) short bf16x8;
typedef __attribute__((ext_vector_type(4))) float f32x4;
typedef __attribute__((ext_vector_type(4))) unsigned int u32x4;

#define AS1 __attribute__((address_space(1)))
#define AS3 __attribute__((address_space(3)))

static __device__ __forceinline__ unsigned short f2bf(float f) {
  unsigned u = __builtin_bit_cast(unsigned, f);
  u += 0x7fffu + ((u >> 16) & 1u);  // RTNE
  return (unsigned short)(u >> 16);
}
static __device__ __forceinline__ float b2f(unsigned short s) {
  unsigned u = ((unsigned)s) << 16;
  return __builtin_bit_cast(float, u);
}

// ---------------------------------------------------------------------------
// bf16 MFMA GEMM, 128x128 tile, R13 choreography (best-measured GEMM config):
// 3 LDS buffers, 2-deep prefetch, counted vmcnt + raw s_barrier, T1 swizzle.
// ---------------------------------------------------------------------------
template <typename TC>
__global__ __launch_bounds__(256) void gemm_bt(
    const unsigned short* __restrict__ A, int lda,   // [M][K] bf16
    const unsigned short* __restrict__ Bt, int ldb,  // [N][K] bf16
    TC* __restrict__ C, int ldc, int K) {
  __shared__ __align__(16) unsigned short As[3][128][32];
  __shared__ __align__(16) unsigned short Bs[3][128][32];

  const int tid = threadIdx.x;
  const int lane = tid & 63, wv = tid >> 6;
  const int m = lane & 15, quad = lane >> 4;
  const int wm = wv >> 1, wn = wv & 1;

  const int gx = gridDim.x;
  const int nwg = gx * gridDim.y;
  const int cpx = nwg >> 3;
  int bid = blockIdx.y * gx + blockIdx.x;
  bid = (bid & 7) * cpx + (bid >> 3);
  const int bm = (bid / gx) * 128, bn = (bid % gx) * 128;

  const int srow = lane >> 2;
  const int gchunk = (lane & 3) ^ ((lane >> 3) & 3);
  const int koff = (quad ^ ((m >> 1) & 3)) * 8;

  f32x4 acc[4][4] = {};

  const unsigned short* Ab = A + (size_t)bm * lda;
  const unsigned short* Bb = Bt + (size_t)bn * ldb;

  auto stage = [&](int k0, int bi) {
#pragma unroll
    for (int j = 0; j < 2; ++j) {
      const int t = wv * 2 + j;
      const int r = t * 16 + srow;
      __builtin_amdgcn_global_load_lds(
          (const AS1 unsigned int*)(Ab + (size_t)r * lda + k0 + gchunk * 8),
          (AS3 unsigned int*)(&As[bi][0][0] + t * 512), 16, 0, 0);
      __builtin_amdgcn_global_load_lds(
          (const AS1 unsigned int*)(Bb + (size_t)r * ldb + k0 + gchunk * 8),
          (AS3 unsigned int*)(&Bs[bi][0][0] + t * 512), 16, 0, 0);
    }
  };

  const int NK = K >> 5;
  stage(0, 0);   // prologue: 2-deep prefetch
  stage(32, 1);

  for (int kt = 0; kt < NK; ++kt) {
    const int bi = kt % 3;
    if (kt < NK - 1)
      asm volatile("s_waitcnt vmcnt(4)" ::: "memory");
    else
      asm volatile("s_waitcnt vmcnt(0)" ::: "memory");
    __builtin_amdgcn_s_barrier();
    if (kt + 2 < NK) stage((kt + 2) * 32, (kt + 2) % 3);

    bf16x8 af[4], bfr[4];
#pragma unroll
    for (int mt = 0; mt < 4; ++mt)
      af[mt] = *(const bf16x8*)&As[bi][wm * 64 + mt * 16 + m][koff];
#pragma unroll
    for (int nt = 0; nt < 4; ++nt)
      bfr[nt] = *(const bf16x8*)&Bs[bi][wn * 64 + nt * 16 + m][koff];
#pragma unroll
    for (int mt = 0; mt < 4; ++mt)
#pragma unroll
      for (int nt = 0; nt < 4; ++nt)
        acc[mt][nt] = __builtin_amdgcn_mfma_f32_16x16x32_bf16(af[mt], bfr[nt], acc[mt][nt], 0, 0, 0);
  }

#pragma unroll
  for (int mt = 0; mt < 4; ++mt) {
#pragma unroll
    for (int reg = 0; reg < 4; ++reg) {
      const size_t row = (size_t)bm + wm * 64 + mt * 16 + quad * 4 + reg;
#pragma unroll
      for (int nt = 0; nt < 4; ++nt) {
        const size_t col = (size_t)bn + wn * 64 + nt * 16 + m;
        float v = acc[mt][nt][reg];
        if constexpr (sizeof(TC) == 4) {
          ((float*)C)[row * ldc + col] = v;
        } else {
          ((unsigned short*)C)[row * ldc + col] = f2bf(v);
        }
      }
    }
  }
}

// ---------------------------------------------------------------------------
// R15: gemm3 + fused V-transpose (harness-verified). kv = ckv @ Wkv_up with
// split epilogue: k_nope tiles -> kvb rows; V tiles -> vtb transposed.
// ---------------------------------------------------------------------------
__global__ __launch_bounds__(256) void gemm_kv(
    const unsigned short* __restrict__ A, int lda,   // [4096][512+] bf16
    const unsigned short* __restrict__ Bt, int ldb,  // [4096][512] bf16
    unsigned short* __restrict__ kvb,                // [bs][4096] (k_nope half)
    unsigned short* __restrict__ vtb,                // [(b*16+h)*128+d][2048]
    int K) {
  __shared__ __align__(16) unsigned short As[3][128][32];
  __shared__ __align__(16) unsigned short Bs[3][128][32];

  const int tid = threadIdx.x;
  const int lane = tid & 63, wv = tid >> 6;
  const int m = lane & 15, quad = lane >> 4;
  const int wm = wv >> 1, wn = wv & 1;

  const int gx = gridDim.x;
  const int nwg = gx * gridDim.y;
  const int cpx = nwg >> 3;
  int bid = blockIdx.y * gx + blockIdx.x;
  bid = (bid & 7) * cpx + (bid >> 3);
  const int bm = (bid / gx) * 128, bn = (bid % gx) * 128;

  const int srow = lane >> 2;
  const int gchunk = (lane & 3) ^ ((lane >> 3) & 3);
  const int koff = (quad ^ ((m >> 1) & 3)) * 8;

  f32x4 acc[4][4] = {};

  const unsigned short* Ab = A + (size_t)bm * lda;
  const unsigned short* Bb = Bt + (size_t)bn * ldb;

  auto stage = [&](int k0, int bi) {
#pragma unroll
    for (int j = 0; j < 2; ++j) {
      const int t = wv * 2 + j;
      const int r = t * 16 + srow;
      __builtin_amdgcn_global_load_lds(
          (const AS1 unsigned int*)(Ab + (size_t)r * lda + k0 + gchunk * 8),
          (AS3 unsigned int*)(&As[bi][0][0] + t * 512), 16, 0, 0);
      __builtin_amdgcn_global_load_lds(
          (const AS1 unsigned int*)(Bb + (size_t)r * ldb + k0 + gchunk * 8),
          (AS3 unsigned int*)(&Bs[bi][0][0] + t * 512), 16, 0, 0);
    }
  };

  const int NK = K >> 5;
  stage(0, 0);
  stage(32, 1);

  for (int kt = 0; kt < NK; ++kt) {
    const int bi = kt % 3;
    if (kt < NK - 1)
      asm volatile("s_waitcnt vmcnt(4)" ::: "memory");
    else
      asm volatile("s_waitcnt vmcnt(0)" ::: "memory");
    __builtin_amdgcn_s_barrier();
    if (kt + 2 < NK) stage((kt + 2) * 32, (kt + 2) % 3);

    bf16x8 af[4], bfr[4];
#pragma unroll
    for (int mt = 0; mt < 4; ++mt)
      af[mt] = *(const bf16x8*)&As[bi][wm * 64 + mt * 16 + m][koff];
#pragma unroll
    for (int nt = 0; nt < 4; ++nt)
      bfr[nt] = *(const bf16x8*)&Bs[bi][wn * 64 + nt * 16 + m][koff];
#pragma unroll
    for (int mt = 0; mt < 4; ++mt)
#pragma unroll
      for (int nt = 0; nt < 4; ++nt)
        acc[mt][nt] = __builtin_amdgcn_mfma_f32_16x16x32_bf16(af[mt], bfr[nt], acc[mt][nt], 0, 0, 0);
  }

  if ((bn & 255) == 0) {
#pragma unroll
    for (int mt = 0; mt < 4; ++mt) {
#pragma unroll
      for (int reg = 0; reg < 4; ++reg) {
        const size_t row = (size_t)bm + wm * 64 + mt * 16 + quad * 4 + reg;
#pragma unroll
        for (int nt = 0; nt < 4; ++nt) {
          const size_t col = (size_t)bn + wn * 64 + nt * 16 + m;
          kvb[row * 4096 + col] = f2bf(acc[mt][nt][reg]);
        }
      }
    }
  } else {
    const int h = bn >> 8;
    const int b = bm >> 11;
    const int sbase = (bm & 2047) + wm * 64 + quad * 4;
#pragma unroll
    for (int nt = 0; nt < 4; ++nt) {
      const int d = wn * 64 + nt * 16 + m;
      unsigned short* vrow = vtb + ((size_t)(b * 16 + h) * 128 + d) * 2048;
#pragma unroll
      for (int mt = 0; mt < 4; ++mt) {
        ushort4 o4;
        o4.x = f2bf(acc[mt][nt][0]);
        o4.y = f2bf(acc[mt][nt][1]);
        o4.z = f2bf(acc[mt][nt][2]);
        o4.w = f2bf(acc[mt][nt][3]);
        *(ushort4*)&vrow[sbase + mt * 16] = o4;
      }
    }
  }
}

// ---------------------------------------------------------------------------
// Weight transpose+cast: W fp32 [K][N] -> Wt bf16 [Npad][K] (zero-pad n>=N).
// ---------------------------------------------------------------------------
__global__ __launch_bounds__(256) void transpose_cast(
    const float* __restrict__ W, int K, int N,
    unsigned short* __restrict__ Wt) {
  __shared__ unsigned short t[32][33];
  const int k0 = blockIdx.x * 32, n0 = blockIdx.y * 32;
  const int tx = threadIdx.x, ty = threadIdx.y;
#pragma unroll
  for (int i = 0; i < 4; ++i) {
    int k = k0 + ty + i * 8, n = n0 + tx;
    float v = (n < N) ? W[(size_t)k * N + n] : 0.0f;
    t[ty + i * 8][tx] = f2bf(v);
  }
  __syncthreads();
#pragma unroll
  for (int i = 0; i < 4; ++i) {
    int n = ty + i * 8;
    Wt[(size_t)(n0 + n) * K + k0 + tx] = t[tx][n];
  }
}

__global__ void cast_bf16(const float* __restrict__ src,
                          unsigned short* __restrict__ dst, int n4) {
  int i = blockIdx.x * blockDim.x + threadIdx.x;
  if (i >= n4) return;
  float4 v = ((const float4*)src)[i];
  ushort4 o;
  o.x = f2bf(v.x); o.y = f2bf(v.y); o.z = f2bf(v.z); o.w = f2bf(v.w);
  ((ushort4*)dst)[i] = o;
}

// ---------------------------------------------------------------------------
// RoPE: qb bf16 in-place; k_rope from qckvb [bs][1664] cols 1536..1599 -> krb.
// R17: powf -> exp2 (one TRANS op).
// ---------------------------------------------------------------------------
__global__ void rope_kernel(unsigned short* __restrict__ qb,
                            const unsigned short* __restrict__ qckvb,
                            unsigned short* __restrict__ krb,
                            const int* __restrict__ position) {
  int idx = blockIdx.x * blockDim.x + threadIdx.x;
  const int total = B_ * S_ * 17 * 32;
  if (idx >= total) return;
  int i = idx & 31;
  int u = idx >> 5;
  int h = u % 17;
  int bs = u / 17;
  int s = bs % S_;
  float pos = (float)position[s];
  float inv_freq = __builtin_amdgcn_exp2f(-(float)i * 0.4152410118609203f);
  float ang = pos * inv_freq;
  float c = cosf(ang), sn = sinf(ang);
  if (h < 16) {
    unsigned short* t = qb + (size_t)bs * 3072 + h * QHEAD_ + NOPE_;
    float t1 = b2f(t[i]), t2 = b2f(t[i + 32]);
    t[i]      = f2bf(t1 * c - t2 * sn);
    t[i + 32] = f2bf(t2 * c + t1 * sn);
  } else {
    const unsigned short* t = qckvb + (size_t)bs * 1664 + 1024 + 512;
    float t1 = b2f(t[i]), t2 = b2f(t[i + 32]);
    krb[(size_t)bs * 64 + i]      = f2bf(t1 * c - t2 * sn);
    krb[(size_t)bs * 64 + i + 32] = f2bf(t2 * c + t1 * sn);
  }
}

// ---------------------------------------------------------------------------
// Flash attention, bf16 MFMA, max-free softmax, Q-tile 128 (4 waves x 32 rows).
// R18 (this round): K-tile 32 -> 64. Halves the per-tile barrier count
// (64 -> 32 __syncthreads/vmcnt(0) drains) — the measured ~23% residual.
// All verified formulas preserved: Ksn (key*128+slot*8) / Ksr (key*64+slot*8)
// rows extend to 64 keys by widening the staging loops only; Vt kept as TWO
// independent 32-key chunks with the exact R10 layout+swizzle; P-path
// (exp2 -> cvt_pk -> bpermute) duplicated per chunk (identical lane algebra,
// pf[ch] from pk[2ch],pk[2ch+1]). o accumulates over both chunks.
// LDS 80 KB -> 2 blocks/CU (= existing grid cap). Grid (S/128, HEADS, B).
// ---------------------------------------------------------------------------
__global__ __launch_bounds__(256) void attn_mfma(
    const unsigned short* __restrict__ qb,   // [bs][3072] bf16, rope applied
    const unsigned short* __restrict__ kvb,  // [bs][4096] bf16 (k_nope per head)
    const unsigned short* __restrict__ krb,  // [bs][64] bf16 roped k_rope
    const unsigned short* __restrict__ vtb,  // [(b*16+h)*128+d][2048] bf16
    unsigned short* __restrict__ aob) {      // [bs][2048] bf16
  __shared__ __align__(16) unsigned short Ksn[2][64 * 128];     // key*128 + slot*8
  __shared__ __align__(16) unsigned short Ksr[2][64 * 64];      // key*64  + slot*8
  __shared__ __align__(16) unsigned short Vt[2][2][128 * 32];   // [ch]: d*32 + slot*8

  const int qt = blockIdx.x, h = blockIdx.y, b = blockIdx.z;
  const int tid = threadIdx.x;
  const int lane = tid & 63, wv = tid >> 6;
  const int m = lane & 15, quad = lane >> 4;
  const int bS = b * S_;
  const int bh = b * 16 + h;
  // 1/sqrt(192) * log2(e): fold softmax scale into exp2 argument
  const float kscale = 0.1041175467f;

  // Q B-fragments for 2 M-tiles (32 q-rows per wave), loaded once
  bf16x8 qf[2][6];
#pragma unroll
  for (int mt2 = 0; mt2 < 2; ++mt2) {
    const unsigned short* qptr =
        qb + (size_t)(bS + qt * 128 + wv * 32 + mt2 * 16 + m) * 3072 + h * QHEAD_ + quad * 8;
#pragma unroll
    for (int c = 0; c < 6; ++c) qf[mt2][c] = *(const bf16x8*)(qptr + c * 32);
  }

  // staging lane constants
  const int kn_keyoff = lane >> 4;                       // 0..3
  const int kr_keyoff = lane >> 3;                       // 0..7
  const int vt_doff   = lane >> 2;                       // 0..15
  const int kr_cc = (lane & 7) ^ (lane >> 3);
  const int vt_cc = (lane & 3) ^ ((lane >> 4) & 3);

  auto stage = [&](int kt, int bi) {
    // K-nope: 64 keys x 256B; 16 instrs; instr i covers keys i*4..i*4+3
#pragma unroll
    for (int j = 0; j < 4; ++j) {
      int i = wv * 4 + j;
      int key = i * 4 + kn_keyoff;
      int cc = (lane & 15) ^ (key & 15);
      __builtin_amdgcn_global_load_lds(
          (const AS1 unsigned int*)(kvb + (size_t)(bS + kt + key) * 4096 + h * 256 + cc * 8),
          (AS3 unsigned int*)(&Ksn[bi][i * 512]), 16, 0, 0);
    }
    // K-rope: 64 keys x 128B; 8 instrs; instr i covers keys i*8..i*8+7
#pragma unroll
    for (int j = 0; j < 2; ++j) {
      int i = wv * 2 + j;
      int key = i * 8 + kr_keyoff;
      __builtin_amdgcn_global_load_lds(
          (const AS1 unsigned int*)(krb + (size_t)(bS + kt + key) * 64 + kr_cc * 8),
          (AS3 unsigned int*)(&Ksr[bi][i * 512]), 16, 0, 0);
    }
    // Vt: 2 chunks of (128 d x 64B); 8 instrs each; chunk ch = keys kt+ch*32..
#pragma unroll
    for (int ch = 0; ch < 2; ++ch)
#pragma unroll
      for (int j = 0; j < 2; ++j) {
        int i = wv * 2 + j;
        int d = i * 16 + vt_doff;
        __builtin_amdgcn_global_load_lds(
            (const AS1 unsigned int*)(vtb + ((size_t)bh * 128 + d) * 2048 + kt + ch * 32 + vt_cc * 8),
            (AS3 unsigned int*)(&Vt[bi][ch][i * 512]), 16, 0, 0);
      }
  };

  const bf16x8 vone = {0x3F80, 0x3F80, 0x3F80, 0x3F80, 0x3F80, 0x3F80, 0x3F80, 0x3F80};

  f32x4 o[2][8] = {};
  f32x4 o9[2] = {};

  stage(0, 0);  // prologue prefetch

  // bpermute gather constants (PV A-frag assembly)
  const int addrA = (((quad & 1) << 5) + m) << 2;
  const int addrB = addrA + 64;
  const bool hiq = (quad >= 2);

  const int NT = S_ / 64;  // 32 tiles
  for (int t = 0; t < NT; ++t) {
    const int bi = t & 1;
    __syncthreads();  // drains vmcnt(0): buf[bi] complete; all waves done reading buf[bi] from 2 iters ago
    if (t + 1 < NT) stage((t + 1) * 64, bi ^ 1);

    // --- QK^T swapped over 64 keys: st[f][mt2], f = 16-key group 0..3 ---
    // C-layout: lane (quad,m): st[f][mt2][r] = S[key=f*16+quad*4+r][q=mt2*16+m]
    f32x4 st[4][2] = {};
    __builtin_amdgcn_s_setprio(1);
#pragma unroll
    for (int c = 0; c < 4; ++c) {  // nope chunks
#pragma unroll
      for (int f = 0; f < 4; ++f) {
        int slot = (c * 4 + quad) ^ m;
        bf16x8 kf = *(const bf16x8*)&Ksn[bi][(f * 16 + m) * 128 + slot * 8];
        st[f][0] = __builtin_amdgcn_mfma_f32_16x16x32_bf16(kf, qf[0][c], st[f][0], 0, 0, 0);
        st[f][1] = __builtin_amdgcn_mfma_f32_16x16x32_bf16(kf, qf[1][c], st[f][1], 0, 0, 0);
      }
    }
#pragma unroll
    for (int c2 = 0; c2 < 2; ++c2) {  // rope chunks
#pragma unroll
      for (int f = 0; f < 4; ++f) {
        int slot = (c2 * 4 + quad) ^ (m & 7);
        bf16x8 kf = *(const bf16x8*)&Ksr[bi][(f * 16 + m) * 64 + slot * 8];
        st[f][0] = __builtin_amdgcn_mfma_f32_16x16x32_bf16(kf, qf[0][4 + c2], st[f][0], 0, 0, 0);
        st[f][1] = __builtin_amdgcn_mfma_f32_16x16x32_bf16(kf, qf[1][4 + c2], st[f][1], 0, 0, 0);
      }
    }
    __builtin_amdgcn_s_setprio(0);

    // --- exp2 (folded scale) -> packed bf16 pairs (consecutive keys) ---
    unsigned int pk[4][2][2];  // [f][mt2][jj]: keys f*16+quad*4+{2jj,2jj+1} @ q=mt2*16+m
#pragma unroll
    for (int f = 0; f < 4; ++f) {
#pragma unroll
      for (int mt2 = 0; mt2 < 2; ++mt2) {
        float e0 = __builtin_amdgcn_exp2f(st[f][mt2][0] * kscale);
        float e1 = __builtin_amdgcn_exp2f(st[f][mt2][1] * kscale);
        float e2 = __builtin_amdgcn_exp2f(st[f][mt2][2] * kscale);
        float e3 = __builtin_amdgcn_exp2f(st[f][mt2][3] * kscale);
        asm("v_cvt_pk_bf16_f32 %0, %1, %2" : "=v"(pk[f][mt2][0]) : "v"(e0), "v"(e1));
        asm("v_cvt_pk_bf16_f32 %0, %1, %2" : "=v"(pk[f][mt2][1]) : "v"(e2), "v"(e3));
      }
    }

    // --- assemble PV A-frags in-register per 32-key chunk: lane (quad,m)
    //     needs P[q=mt2*16+m][keys ch*32 + quad*8..quad*8+7] ---
    bf16x8 pf[2][2];  // [ch][mt2]
#pragma unroll
    for (int ch = 0; ch < 2; ++ch) {
#pragma unroll
      for (int mt2 = 0; mt2 < 2; ++mt2) {
        unsigned int w0a = (unsigned)__builtin_amdgcn_ds_bpermute(addrA, (int)pk[2 * ch][mt2][0]);
        unsigned int w0b = (unsigned)__builtin_amdgcn_ds_bpermute(addrA, (int)pk[2 * ch + 1][mt2][0]);
        unsigned int w1a = (unsigned)__builtin_amdgcn_ds_bpermute(addrA, (int)pk[2 * ch][mt2][1]);
        unsigned int w1b = (unsigned)__builtin_amdgcn_ds_bpermute(addrA, (int)pk[2 * ch + 1][mt2][1]);
        unsigned int w2a = (unsigned)__builtin_amdgcn_ds_bpermute(addrB, (int)pk[2 * ch][mt2][0]);
        unsigned int w2b = (unsigned)__builtin_amdgcn_ds_bpermute(addrB, (int)pk[2 * ch + 1][mt2][0]);
        unsigned int w3a = (unsigned)__builtin_amdgcn_ds_bpermute(addrB, (int)pk[2 * ch][mt2][1]);
        unsigned int w3b = (unsigned)__builtin_amdgcn_ds_bpermute(addrB, (int)pk[2 * ch + 1][mt2][1]);
        u32x4 wreg = {hiq ? w0b : w0a, hiq ? w1b : w1a, hiq ? w2b : w2a, hiq ? w3b : w3a};
        pf[ch][mt2] = __builtin_bit_cast(bf16x8, wreg);
      }
    }

    // --- PV: 2 chunks x (K=32 MFMA); each V-frag read feeds both M-tiles ---
    const int vslot = quad ^ ((m >> 2) & 3);
    __builtin_amdgcn_s_setprio(1);
#pragma unroll
    for (int ch = 0; ch < 2; ++ch) {
#pragma unroll
      for (int nt = 0; nt < 8; ++nt) {
        bf16x8 vf = *(const bf16x8*)&Vt[bi][ch][(nt * 16 + m) * 32 + vslot * 8];
        o[0][nt] = __builtin_amdgcn_mfma_f32_16x16x32_bf16(pf[ch][0], vf, o[0][nt], 0, 0, 0);
        o[1][nt] = __builtin_amdgcn_mfma_f32_16x16x32_bf16(pf[ch][1], vf, o[1][nt], 0, 0, 0);
      }
      o9[0] = __builtin_amdgcn_mfma_f32_16x16x32_bf16(pf[ch][0], vone, o9[0], 0, 0, 0);
      o9[1] = __builtin_amdgcn_mfma_f32_16x16x32_bf16(pf[ch][1], vone, o9[1], 0, 0, 0);
    }
    __builtin_amdgcn_s_setprio(0);
  }

#pragma unroll
  for (int mt2 = 0; mt2 < 2; ++mt2) {
#pragma unroll
    for (int r = 0; r < 4; ++r) {
      float inv = 1.0f / o9[mt2][r];
      size_t row = (size_t)(bS + qt * 128 + wv * 32 + mt2 * 16 + quad * 4 + r);
#pragma unroll
      for (int nt = 0; nt < 8; ++nt)
        aob[row * 2048 + h * VHEAD_ + nt * 16 + m] = f2bf(o[mt2][nt][r] * inv);
    }
  }
}

// ---------------------------------------------------------------------------
extern "C" void kernel_launch(void* const* d_in, const int* in_sizes, int n_in,
                              void* d_out, int out_size, void* d_ws, size_t ws_size,
                              hipStream_t stream) {
  const float* x        = (const float*)d_in[0];
  const int*   position = (const int*)d_in[1];
  const float* Wq_down  = (const float*)d_in[2];  // [2048,1024]
  const float* Wq_up    = (const float*)d_in[3];  // [1024,3072]
  const float* Wkv_down = (const float*)d_in[4];  // [2048,576]
  const float* Wkv_up   = (const float*)d_in[5];  // [512,4096]
  const float* Wout     = (const float*)d_in[6];  // [2048,2048]
  float* out = (float*)d_out;

  char* w = (char*)d_ws;
  size_t off = 0;
  auto alloc = [&](size_t bytes) { char* p = w + off; off += (bytes + 255) & ~size_t(255); return p; };
  unsigned short* xb      = (unsigned short*)alloc(4096ull * 2048 * 2);
  unsigned short* qckvb   = (unsigned short*)alloc(4096ull * 1664 * 2);  // [qdown | ckv(640)]
  unsigned short* qb      = (unsigned short*)alloc(4096ull * 3072 * 2);
  unsigned short* kvb     = (unsigned short*)alloc(4096ull * 4096 * 2);
  unsigned short* vtb     = (unsigned short*)alloc(32ull * 128 * 2048 * 2);
  unsigned short* krb     = (unsigned short*)alloc(4096ull * 64 * 2);
  unsigned short* aob     = (unsigned short*)alloc(4096ull * 2048 * 2);
  unsigned short* Wqdkv_t = (unsigned short*)alloc(1664ull * 2048 * 2);  // [Wqd^T | Wkvd^T(640)]
  unsigned short* Wqu_t   = (unsigned short*)alloc(3072ull * 1024 * 2);
  unsigned short* Wkvu_t  = (unsigned short*)alloc(4096ull * 512 * 2);
  unsigned short* Wout_t  = (unsigned short*)alloc(2048ull * 2048 * 2);

  dim3 tblk(32, 8);

  cast_bf16<<<(4096 * 2048 / 4 + 255) / 256, 256, 0, stream>>>(x, xb, 4096 * 2048 / 4);
  transpose_cast<<<dim3(2048 / 32, 1024 / 32), tblk, 0, stream>>>(Wq_down, 2048, 1024, Wqdkv_t);
  transpose_cast<<<dim3(2048 / 32, 640 / 32), tblk, 0, stream>>>(Wkv_down, 2048, 576, Wqdkv_t + 1024ull * 2048);
  transpose_cast<<<dim3(1024 / 32, 3072 / 32), tblk, 0, stream>>>(Wq_up, 1024, 3072, Wqu_t);
  transpose_cast<<<dim3(512 / 32, 4096 / 32), tblk, 0, stream>>>(Wkv_up, 512, 4096, Wkvu_t);
  transpose_cast<<<dim3(2048 / 32, 2048 / 32), tblk, 0, stream>>>(Wout, 2048, 2048, Wout_t);

  // fused: [qdown | ckv] = xb @ [Wq_down | Wkv_down]  (M=4096, N=1664, K=2048)
  gemm_bt<unsigned short><<<dim3(1664 / 128, 32), 256, 0, stream>>>(
      xb, 2048, Wqdkv_t, 2048, qckvb, 1664, 2048);
  // qb = qdown @ Wq_up (N=3072, K=1024)
  gemm_bt<unsigned short><<<dim3(3072 / 128, 32), 256, 0, stream>>>(
      qckvb, 1664, Wqu_t, 1024, qb, 3072, 1024);
  // rope
  {
    int total = B_ * S_ * 17 * 32;
    rope_kernel<<<(total + 255) / 256, 256, 0, stream>>>(qb, qckvb, krb, position);
  }
  // kv = ckv[:, :512] @ Wkv_up (N=4096, K=512) with fused V-transpose:
  // k_nope cols -> kvb, V cols -> vtb (transposed). Replaces pack_vt.
  gemm_kv<<<dim3(4096 / 128, 32), 256, 0, stream>>>(
      qckvb + 1024, 1664, Wkvu_t, 512, kvb, vtb, 512);
  // attention -> aob (bf16), Q-tile 128, K-tile 64, double-buffered pipeline
  attn_mfma<<<dim3(S_ / 128, HEADS_, B_), 256, 0, stream>>>(qb, kvb, krb, vtb, aob);
  // out = aob @ Wout (fp32 out)
  gemm_bt<float><<<dim3(2048 / 128, 32), 256, 0, stream>>>(
      aob, 2048, Wout_t, 2048, out, 2048, 2048);
}

// Round 14
// 421.480 us; speedup vs baseline: 1.1360x; 1.1360x over previous
//
#include <hip/hip_runtime.h>
#include <math.h>

#define B_      2
#define S_      2048
#define HIDDEN_ 2048
#define HEADS_  16
#define QLORA_  1024
#define KVLORA_ 512
#define NOPE_   128
#define ROPE_   64
#define QHEAD_  192
#define VHEAD_  128

typedef __attribute__((ext_vector_type(8))) short bf16x8;
typedef __attribute__((ext_vector_type(4))) float f32x4;
typedef __attribute__((ext_vector_type(4))) unsigned int u32x4;

#define AS1 __attribute__((address_space(1)))
#define AS3 __attribute__((address_space(3)))

static __device__ __forceinline__ unsigned short f2bf(float f) {
  unsigned u = __builtin_bit_cast(unsigned, f);
  u += 0x7fffu + ((u >> 16) & 1u);  // RTNE
  return (unsigned short)(u >> 16);
}
static __device__ __forceinline__ float b2f(unsigned short s) {
  unsigned u = ((unsigned)s) << 16;
  return __builtin_bit_cast(float, u);
}

// ---------------------------------------------------------------------------
// bf16 MFMA GEMM, 128x128 tile, R13 choreography (best-measured GEMM config):
// 3 LDS buffers, 2-deep prefetch, counted vmcnt + raw s_barrier, T1 swizzle.
// R19: R18's attn K-tile-64 reverted (80KB LDS = exactly half the pool ->
// only 1 block/CU launched (occupancy 21->11%), losing the co-resident-block
// latency hiding; attn 126->180us. Keep LDS strictly below pool/2.)
// This file is the R17 measured-best (423.1 us) restored verbatim.
// ---------------------------------------------------------------------------
template <typename TC>
__global__ __launch_bounds__(256) void gemm_bt(
    const unsigned short* __restrict__ A, int lda,   // [M][K] bf16
    const unsigned short* __restrict__ Bt, int ldb,  // [N][K] bf16
    TC* __restrict__ C, int ldc, int K) {
  __shared__ __align__(16) unsigned short As[3][128][32];
  __shared__ __align__(16) unsigned short Bs[3][128][32];

  const int tid = threadIdx.x;
  const int lane = tid & 63, wv = tid >> 6;
  const int m = lane & 15, quad = lane >> 4;
  const int wm = wv >> 1, wn = wv & 1;

  const int gx = gridDim.x;
  const int nwg = gx * gridDim.y;
  const int cpx = nwg >> 3;
  int bid = blockIdx.y * gx + blockIdx.x;
  bid = (bid & 7) * cpx + (bid >> 3);
  const int bm = (bid / gx) * 128, bn = (bid % gx) * 128;

  const int srow = lane >> 2;
  const int gchunk = (lane & 3) ^ ((lane >> 3) & 3);
  const int koff = (quad ^ ((m >> 1) & 3)) * 8;

  f32x4 acc[4][4] = {};

  const unsigned short* Ab = A + (size_t)bm * lda;
  const unsigned short* Bb = Bt + (size_t)bn * ldb;

  auto stage = [&](int k0, int bi) {
#pragma unroll
    for (int j = 0; j < 2; ++j) {
      const int t = wv * 2 + j;
      const int r = t * 16 + srow;
      __builtin_amdgcn_global_load_lds(
          (const AS1 unsigned int*)(Ab + (size_t)r * lda + k0 + gchunk * 8),
          (AS3 unsigned int*)(&As[bi][0][0] + t * 512), 16, 0, 0);
      __builtin_amdgcn_global_load_lds(
          (const AS1 unsigned int*)(Bb + (size_t)r * ldb + k0 + gchunk * 8),
          (AS3 unsigned int*)(&Bs[bi][0][0] + t * 512), 16, 0, 0);
    }
  };

  const int NK = K >> 5;
  stage(0, 0);   // prologue: 2-deep prefetch
  stage(32, 1);

  for (int kt = 0; kt < NK; ++kt) {
    const int bi = kt % 3;
    if (kt < NK - 1)
      asm volatile("s_waitcnt vmcnt(4)" ::: "memory");
    else
      asm volatile("s_waitcnt vmcnt(0)" ::: "memory");
    __builtin_amdgcn_s_barrier();
    if (kt + 2 < NK) stage((kt + 2) * 32, (kt + 2) % 3);

    bf16x8 af[4], bfr[4];
#pragma unroll
    for (int mt = 0; mt < 4; ++mt)
      af[mt] = *(const bf16x8*)&As[bi][wm * 64 + mt * 16 + m][koff];
#pragma unroll
    for (int nt = 0; nt < 4; ++nt)
      bfr[nt] = *(const bf16x8*)&Bs[bi][wn * 64 + nt * 16 + m][koff];
#pragma unroll
    for (int mt = 0; mt < 4; ++mt)
#pragma unroll
      for (int nt = 0; nt < 4; ++nt)
        acc[mt][nt] = __builtin_amdgcn_mfma_f32_16x16x32_bf16(af[mt], bfr[nt], acc[mt][nt], 0, 0, 0);
  }

#pragma unroll
  for (int mt = 0; mt < 4; ++mt) {
#pragma unroll
    for (int reg = 0; reg < 4; ++reg) {
      const size_t row = (size_t)bm + wm * 64 + mt * 16 + quad * 4 + reg;
#pragma unroll
      for (int nt = 0; nt < 4; ++nt) {
        const size_t col = (size_t)bn + wn * 64 + nt * 16 + m;
        float v = acc[mt][nt][reg];
        if constexpr (sizeof(TC) == 4) {
          ((float*)C)[row * ldc + col] = v;
        } else {
          ((unsigned short*)C)[row * ldc + col] = f2bf(v);
        }
      }
    }
  }
}

// ---------------------------------------------------------------------------
// R15: gemm3 + fused V-transpose (harness-verified). kv = ckv @ Wkv_up with
// split epilogue: k_nope tiles -> kvb rows; V tiles -> vtb transposed.
// ---------------------------------------------------------------------------
__global__ __launch_bounds__(256) void gemm_kv(
    const unsigned short* __restrict__ A, int lda,   // [4096][512+] bf16
    const unsigned short* __restrict__ Bt, int ldb,  // [4096][512] bf16
    unsigned short* __restrict__ kvb,                // [bs][4096] (k_nope half)
    unsigned short* __restrict__ vtb,                // [(b*16+h)*128+d][2048]
    int K) {
  __shared__ __align__(16) unsigned short As[3][128][32];
  __shared__ __align__(16) unsigned short Bs[3][128][32];

  const int tid = threadIdx.x;
  const int lane = tid & 63, wv = tid >> 6;
  const int m = lane & 15, quad = lane >> 4;
  const int wm = wv >> 1, wn = wv & 1;

  const int gx = gridDim.x;
  const int nwg = gx * gridDim.y;
  const int cpx = nwg >> 3;
  int bid = blockIdx.y * gx + blockIdx.x;
  bid = (bid & 7) * cpx + (bid >> 3);
  const int bm = (bid / gx) * 128, bn = (bid % gx) * 128;

  const int srow = lane >> 2;
  const int gchunk = (lane & 3) ^ ((lane >> 3) & 3);
  const int koff = (quad ^ ((m >> 1) & 3)) * 8;

  f32x4 acc[4][4] = {};

  const unsigned short* Ab = A + (size_t)bm * lda;
  const unsigned short* Bb = Bt + (size_t)bn * ldb;

  auto stage = [&](int k0, int bi) {
#pragma unroll
    for (int j = 0; j < 2; ++j) {
      const int t = wv * 2 + j;
      const int r = t * 16 + srow;
      __builtin_amdgcn_global_load_lds(
          (const AS1 unsigned int*)(Ab + (size_t)r * lda + k0 + gchunk * 8),
          (AS3 unsigned int*)(&As[bi][0][0] + t * 512), 16, 0, 0);
      __builtin_amdgcn_global_load_lds(
          (const AS1 unsigned int*)(Bb + (size_t)r * ldb + k0 + gchunk * 8),
          (AS3 unsigned int*)(&Bs[bi][0][0] + t * 512), 16, 0, 0);
    }
  };

  const int NK = K >> 5;
  stage(0, 0);
  stage(32, 1);

  for (int kt = 0; kt < NK; ++kt) {
    const int bi = kt % 3;
    if (kt < NK - 1)
      asm volatile("s_waitcnt vmcnt(4)" ::: "memory");
    else
      asm volatile("s_waitcnt vmcnt(0)" ::: "memory");
    __builtin_amdgcn_s_barrier();
    if (kt + 2 < NK) stage((kt + 2) * 32, (kt + 2) % 3);

    bf16x8 af[4], bfr[4];
#pragma unroll
    for (int mt = 0; mt < 4; ++mt)
      af[mt] = *(const bf16x8*)&As[bi][wm * 64 + mt * 16 + m][koff];
#pragma unroll
    for (int nt = 0; nt < 4; ++nt)
      bfr[nt] = *(const bf16x8*)&Bs[bi][wn * 64 + nt * 16 + m][koff];
#pragma unroll
    for (int mt = 0; mt < 4; ++mt)
#pragma unroll
      for (int nt = 0; nt < 4; ++nt)
        acc[mt][nt] = __builtin_amdgcn_mfma_f32_16x16x32_bf16(af[mt], bfr[nt], acc[mt][nt], 0, 0, 0);
  }

  if ((bn & 255) == 0) {
#pragma unroll
    for (int mt = 0; mt < 4; ++mt) {
#pragma unroll
      for (int reg = 0; reg < 4; ++reg) {
        const size_t row = (size_t)bm + wm * 64 + mt * 16 + quad * 4 + reg;
#pragma unroll
        for (int nt = 0; nt < 4; ++nt) {
          const size_t col = (size_t)bn + wn * 64 + nt * 16 + m;
          kvb[row * 4096 + col] = f2bf(acc[mt][nt][reg]);
        }
      }
    }
  } else {
    const int h = bn >> 8;
    const int b = bm >> 11;
    const int sbase = (bm & 2047) + wm * 64 + quad * 4;
#pragma unroll
    for (int nt = 0; nt < 4; ++nt) {
      const int d = wn * 64 + nt * 16 + m;
      unsigned short* vrow = vtb + ((size_t)(b * 16 + h) * 128 + d) * 2048;
#pragma unroll
      for (int mt = 0; mt < 4; ++mt) {
        ushort4 o4;
        o4.x = f2bf(acc[mt][nt][0]);
        o4.y = f2bf(acc[mt][nt][1]);
        o4.z = f2bf(acc[mt][nt][2]);
        o4.w = f2bf(acc[mt][nt][3]);
        *(ushort4*)&vrow[sbase + mt * 16] = o4;
      }
    }
  }
}

// ---------------------------------------------------------------------------
// Weight transpose+cast: W fp32 [K][N] -> Wt bf16 [Npad][K] (zero-pad n>=N).
// ---------------------------------------------------------------------------
__global__ __launch_bounds__(256) void transpose_cast(
    const float* __restrict__ W, int K, int N,
    unsigned short* __restrict__ Wt) {
  __shared__ unsigned short t[32][33];
  const int k0 = blockIdx.x * 32, n0 = blockIdx.y * 32;
  const int tx = threadIdx.x, ty = threadIdx.y;
#pragma unroll
  for (int i = 0; i < 4; ++i) {
    int k = k0 + ty + i * 8, n = n0 + tx;
    float v = (n < N) ? W[(size_t)k * N + n] : 0.0f;
    t[ty + i * 8][tx] = f2bf(v);
  }
  __syncthreads();
#pragma unroll
  for (int i = 0; i < 4; ++i) {
    int n = ty + i * 8;
    Wt[(size_t)(n0 + n) * K + k0 + tx] = t[tx][n];
  }
}

__global__ void cast_bf16(const float* __restrict__ src,
                          unsigned short* __restrict__ dst, int n4) {
  int i = blockIdx.x * blockDim.x + threadIdx.x;
  if (i >= n4) return;
  float4 v = ((const float4*)src)[i];
  ushort4 o;
  o.x = f2bf(v.x); o.y = f2bf(v.y); o.z = f2bf(v.z); o.w = f2bf(v.w);
  ((ushort4*)dst)[i] = o;
}

// ---------------------------------------------------------------------------
// RoPE: qb bf16 in-place; k_rope from qckvb [bs][1664] cols 1536..1599 -> krb.
// R17: powf -> exp2 (one TRANS op).
// ---------------------------------------------------------------------------
__global__ void rope_kernel(unsigned short* __restrict__ qb,
                            const unsigned short* __restrict__ qckvb,
                            unsigned short* __restrict__ krb,
                            const int* __restrict__ position) {
  int idx = blockIdx.x * blockDim.x + threadIdx.x;
  const int total = B_ * S_ * 17 * 32;
  if (idx >= total) return;
  int i = idx & 31;
  int u = idx >> 5;
  int h = u % 17;
  int bs = u / 17;
  int s = bs % S_;
  float pos = (float)position[s];
  float inv_freq = __builtin_amdgcn_exp2f(-(float)i * 0.4152410118609203f);
  float ang = pos * inv_freq;
  float c = cosf(ang), sn = sinf(ang);
  if (h < 16) {
    unsigned short* t = qb + (size_t)bs * 3072 + h * QHEAD_ + NOPE_;
    float t1 = b2f(t[i]), t2 = b2f(t[i + 32]);
    t[i]      = f2bf(t1 * c - t2 * sn);
    t[i + 32] = f2bf(t2 * c + t1 * sn);
  } else {
    const unsigned short* t = qckvb + (size_t)bs * 1664 + 1024 + 512;
    float t1 = b2f(t[i]), t2 = b2f(t[i + 32]);
    krb[(size_t)bs * 64 + i]      = f2bf(t1 * c - t2 * sn);
    krb[(size_t)bs * 64 + i + 32] = f2bf(t2 * c + t1 * sn);
  }
}

// ---------------------------------------------------------------------------
// Flash attention, bf16 MFMA, max-free softmax, Q-tile 128 (4 waves x 32 rows).
// R10 kernel verbatim (126-128 µs known-good):
//   R7 double-buffered K-tile-32 single-barrier pipeline; R9 exp2+setprio;
//   R10 swapped-QK^T + cvt_pk + bpermute in-register P path, Vt swizzle.
// LDS 40 KB. Grid (S/128, HEADS, B) = 512 blocks.
// ---------------------------------------------------------------------------
__global__ __launch_bounds__(256) void attn_mfma(
    const unsigned short* __restrict__ qb,   // [bs][3072] bf16, rope applied
    const unsigned short* __restrict__ kvb,  // [bs][4096] bf16 (k_nope per head)
    const unsigned short* __restrict__ krb,  // [bs][64] bf16 roped k_rope
    const unsigned short* __restrict__ vtb,  // [(b*16+h)*128+d][2048] bf16
    unsigned short* __restrict__ aob) {      // [bs][2048] bf16
  __shared__ __align__(16) unsigned short Ksn[2][32 * 128];  // key*128 + slot*8
  __shared__ __align__(16) unsigned short Ksr[2][32 * 64];   // key*64  + slot*8
  __shared__ __align__(16) unsigned short Vt[2][128 * 32];   // d*32    + slot*8

  const int qt = blockIdx.x, h = blockIdx.y, b = blockIdx.z;
  const int tid = threadIdx.x;
  const int lane = tid & 63, wv = tid >> 6;
  const int m = lane & 15, quad = lane >> 4;
  const int bS = b * S_;
  const int bh = b * 16 + h;
  // 1/sqrt(192) * log2(e): fold softmax scale into exp2 argument
  const float kscale = 0.1041175467f;

  // Q B-fragments for 2 M-tiles (32 q-rows per wave), loaded once
  bf16x8 qf[2][6];
#pragma unroll
  for (int mt2 = 0; mt2 < 2; ++mt2) {
    const unsigned short* qptr =
        qb + (size_t)(bS + qt * 128 + wv * 32 + mt2 * 16 + m) * 3072 + h * QHEAD_ + quad * 8;
#pragma unroll
    for (int c = 0; c < 6; ++c) qf[mt2][c] = *(const bf16x8*)(qptr + c * 32);
  }

  // staging lane constants
  const int kn_keyoff = lane >> 4;                       // 0..3
  const int kr_keyoff = lane >> 3;                       // 0..7
  const int vt_doff   = lane >> 2;                       // 0..15
  const int kr_cc = (lane & 7) ^ (lane >> 3);
  const int vt_cc = (lane & 3) ^ ((lane >> 4) & 3);

  auto stage = [&](int kt, int bi) {
    // K-nope: 32 keys x 256B; 8 instrs; instr i covers keys i*4..i*4+3
#pragma unroll
    for (int j = 0; j < 2; ++j) {
      int i = wv * 2 + j;
      int key = i * 4 + kn_keyoff;
      int cc = (lane & 15) ^ (key & 15);
      __builtin_amdgcn_global_load_lds(
          (const AS1 unsigned int*)(kvb + (size_t)(bS + kt + key) * 4096 + h * 256 + cc * 8),
          (AS3 unsigned int*)(&Ksn[bi][i * 512]), 16, 0, 0);
    }
    // K-rope: 32 keys x 128B; 4 instrs; instr i covers keys i*8..i*8+7
    {
      int i = wv;
      int key = i * 8 + kr_keyoff;
      __builtin_amdgcn_global_load_lds(
          (const AS1 unsigned int*)(krb + (size_t)(bS + kt + key) * 64 + kr_cc * 8),
          (AS3 unsigned int*)(&Ksr[bi][i * 512]), 16, 0, 0);
    }
    // Vt: 128 d x 64B; 8 instrs; instr i covers d i*16..i*16+15
#pragma unroll
    for (int j = 0; j < 2; ++j) {
      int i = wv * 2 + j;
      int d = i * 16 + vt_doff;
      __builtin_amdgcn_global_load_lds(
          (const AS1 unsigned int*)(vtb + ((size_t)bh * 128 + d) * 2048 + kt + vt_cc * 8),
          (AS3 unsigned int*)(&Vt[bi][i * 512]), 16, 0, 0);
    }
  };

  const bf16x8 vone = {0x3F80, 0x3F80, 0x3F80, 0x3F80, 0x3F80, 0x3F80, 0x3F80, 0x3F80};

  f32x4 o[2][8] = {};
  f32x4 o9[2] = {};

  stage(0, 0);  // prologue prefetch

  // bpermute gather constants (PV A-frag assembly)
  const int addrA = (((quad & 1) << 5) + m) << 2;
  const int addrB = addrA + 64;
  const bool hiq = (quad >= 2);

  const int NT = S_ / 32;  // 64 tiles
  for (int t = 0; t < NT; ++t) {
    const int bi = t & 1;
    __syncthreads();  // drains vmcnt(0): buf[bi] complete; all waves done reading buf[bi] from 2 iters ago
    if (t + 1 < NT) stage((t + 1) * 32, bi ^ 1);

    // --- QK^T swapped: st[f][mt2] = K_tile_f^T-frag x Q_tile_mt2 -> S^T ---
    // C-layout: lane (quad,m): st[f][mt2][r] = S[key=f*16+quad*4+r][q=mt2*16+m]
    f32x4 st[2][2] = {};
    __builtin_amdgcn_s_setprio(1);
#pragma unroll
    for (int c = 0; c < 4; ++c) {  // nope chunks
#pragma unroll
      for (int f = 0; f < 2; ++f) {
        int slot = (c * 4 + quad) ^ m;
        bf16x8 kf = *(const bf16x8*)&Ksn[bi][(f * 16 + m) * 128 + slot * 8];
        st[f][0] = __builtin_amdgcn_mfma_f32_16x16x32_bf16(kf, qf[0][c], st[f][0], 0, 0, 0);
        st[f][1] = __builtin_amdgcn_mfma_f32_16x16x32_bf16(kf, qf[1][c], st[f][1], 0, 0, 0);
      }
    }
#pragma unroll
    for (int c2 = 0; c2 < 2; ++c2) {  // rope chunks
#pragma unroll
      for (int f = 0; f < 2; ++f) {
        int slot = (c2 * 4 + quad) ^ (m & 7);
        bf16x8 kf = *(const bf16x8*)&Ksr[bi][(f * 16 + m) * 64 + slot * 8];
        st[f][0] = __builtin_amdgcn_mfma_f32_16x16x32_bf16(kf, qf[0][4 + c2], st[f][0], 0, 0, 0);
        st[f][1] = __builtin_amdgcn_mfma_f32_16x16x32_bf16(kf, qf[1][4 + c2], st[f][1], 0, 0, 0);
      }
    }
    __builtin_amdgcn_s_setprio(0);

    // --- exp2 (folded scale) -> packed bf16 pairs (consecutive keys) ---
    unsigned int pk[2][2][2];  // [f][mt2][jj]: keys f*16+quad*4+{2jj,2jj+1} @ q=mt2*16+m
#pragma unroll
    for (int f = 0; f < 2; ++f) {
#pragma unroll
      for (int mt2 = 0; mt2 < 2; ++mt2) {
        float e0 = __builtin_amdgcn_exp2f(st[f][mt2][0] * kscale);
        float e1 = __builtin_amdgcn_exp2f(st[f][mt2][1] * kscale);
        float e2 = __builtin_amdgcn_exp2f(st[f][mt2][2] * kscale);
        float e3 = __builtin_amdgcn_exp2f(st[f][mt2][3] * kscale);
        asm("v_cvt_pk_bf16_f32 %0, %1, %2" : "=v"(pk[f][mt2][0]) : "v"(e0), "v"(e1));
        asm("v_cvt_pk_bf16_f32 %0, %1, %2" : "=v"(pk[f][mt2][1]) : "v"(e2), "v"(e3));
      }
    }

    // --- assemble PV A-frags in-register: lane (quad,m) needs
    //     P[q=mt2*16+m][keys quad*8..quad*8+7] ---
    bf16x8 pf[2];
#pragma unroll
    for (int mt2 = 0; mt2 < 2; ++mt2) {
      unsigned int w0a = (unsigned)__builtin_amdgcn_ds_bpermute(addrA, (int)pk[0][mt2][0]);
      unsigned int w0b = (unsigned)__builtin_amdgcn_ds_bpermute(addrA, (int)pk[1][mt2][0]);
      unsigned int w1a = (unsigned)__builtin_amdgcn_ds_bpermute(addrA, (int)pk[0][mt2][1]);
      unsigned int w1b = (unsigned)__builtin_amdgcn_ds_bpermute(addrA, (int)pk[1][mt2][1]);
      unsigned int w2a = (unsigned)__builtin_amdgcn_ds_bpermute(addrB, (int)pk[0][mt2][0]);
      unsigned int w2b = (unsigned)__builtin_amdgcn_ds_bpermute(addrB, (int)pk[1][mt2][0]);
      unsigned int w3a = (unsigned)__builtin_amdgcn_ds_bpermute(addrB, (int)pk[0][mt2][1]);
      unsigned int w3b = (unsigned)__builtin_amdgcn_ds_bpermute(addrB, (int)pk[1][mt2][1]);
      u32x4 wreg = {hiq ? w0b : w0a, hiq ? w1b : w1a, hiq ? w2b : w2a, hiq ? w3b : w3a};
      pf[mt2] = __builtin_bit_cast(bf16x8, wreg);
    }

    // --- PV (one K=32 MFMA chunk): each V-frag read feeds both M-tiles ---
    const int vslot = quad ^ ((m >> 2) & 3);
    __builtin_amdgcn_s_setprio(1);
#pragma unroll
    for (int nt = 0; nt < 8; ++nt) {
      bf16x8 vf = *(const bf16x8*)&Vt[bi][(nt * 16 + m) * 32 + vslot * 8];
      o[0][nt] = __builtin_amdgcn_mfma_f32_16x16x32_bf16(pf[0], vf, o[0][nt], 0, 0, 0);
      o[1][nt] = __builtin_amdgcn_mfma_f32_16x16x32_bf16(pf[1], vf, o[1][nt], 0, 0, 0);
    }
    o9[0] = __builtin_amdgcn_mfma_f32_16x16x32_bf16(pf[0], vone, o9[0], 0, 0, 0);
    o9[1] = __builtin_amdgcn_mfma_f32_16x16x32_bf16(pf[1], vone, o9[1], 0, 0, 0);
    __builtin_amdgcn_s_setprio(0);
  }

#pragma unroll
  for (int mt2 = 0; mt2 < 2; ++mt2) {
#pragma unroll
    for (int r = 0; r < 4; ++r) {
      float inv = 1.0f / o9[mt2][r];
      size_t row = (size_t)(bS + qt * 128 + wv * 32 + mt2 * 16 + quad * 4 + r);
#pragma unroll
      for (int nt = 0; nt < 8; ++nt)
        aob[row * 2048 + h * VHEAD_ + nt * 16 + m] = f2bf(o[mt2][nt][r] * inv);
    }
  }
}

// ---------------------------------------------------------------------------
extern "C" void kernel_launch(void* const* d_in, const int* in_sizes, int n_in,
                              void* d_out, int out_size, void* d_ws, size_t ws_size,
                              hipStream_t stream) {
  const float* x        = (const float*)d_in[0];
  const int*   position = (const int*)d_in[1];
  const float* Wq_down  = (const float*)d_in[2];  // [2048,1024]
  const float* Wq_up    = (const float*)d_in[3];  // [1024,3072]
  const float* Wkv_down = (const float*)d_in[4];  // [2048,576]
  const float* Wkv_up   = (const float*)d_in[5];  // [512,4096]
  const float* Wout     = (const float*)d_in[6];  // [2048,2048]
  float* out = (float*)d_out;

  char* w = (char*)d_ws;
  size_t off = 0;
  auto alloc = [&](size_t bytes) { char* p = w + off; off += (bytes + 255) & ~size_t(255); return p; };
  unsigned short* xb      = (unsigned short*)alloc(4096ull * 2048 * 2);
  unsigned short* qckvb   = (unsigned short*)alloc(4096ull * 1664 * 2);  // [qdown | ckv(640)]
  unsigned short* qb      = (unsigned short*)alloc(4096ull * 3072 * 2);
  unsigned short* kvb     = (unsigned short*)alloc(4096ull * 4096 * 2);
  unsigned short* vtb     = (unsigned short*)alloc(32ull * 128 * 2048 * 2);
  unsigned short* krb     = (unsigned short*)alloc(4096ull * 64 * 2);
  unsigned short* aob     = (unsigned short*)alloc(4096ull * 2048 * 2);
  unsigned short* Wqdkv_t = (unsigned short*)alloc(1664ull * 2048 * 2);  // [Wqd^T | Wkvd^T(640)]
  unsigned short* Wqu_t   = (unsigned short*)alloc(3072ull * 1024 * 2);
  unsigned short* Wkvu_t  = (unsigned short*)alloc(4096ull * 512 * 2);
  unsigned short* Wout_t  = (unsigned short*)alloc(2048ull * 2048 * 2);

  dim3 tblk(32, 8);

  cast_bf16<<<(4096 * 2048 / 4 + 255) / 256, 256, 0, stream>>>(x, xb, 4096 * 2048 / 4);
  transpose_cast<<<dim3(2048 / 32, 1024 / 32), tblk, 0, stream>>>(Wq_down, 2048, 1024, Wqdkv_t);
  transpose_cast<<<dim3(2048 / 32, 640 / 32), tblk, 0, stream>>>(Wkv_down, 2048, 576, Wqdkv_t + 1024ull * 2048);
  transpose_cast<<<dim3(1024 / 32, 3072 / 32), tblk, 0, stream>>>(Wq_up, 1024, 3072, Wqu_t);
  transpose_cast<<<dim3(512 / 32, 4096 / 32), tblk, 0, stream>>>(Wkv_up, 512, 4096, Wkvu_t);
  transpose_cast<<<dim3(2048 / 32, 2048 / 32), tblk, 0, stream>>>(Wout, 2048, 2048, Wout_t);

  // fused: [qdown | ckv] = xb @ [Wq_down | Wkv_down]  (M=4096, N=1664, K=2048)
  gemm_bt<unsigned short><<<dim3(1664 / 128, 32), 256, 0, stream>>>(
      xb, 2048, Wqdkv_t, 2048, qckvb, 1664, 2048);
  // qb = qdown @ Wq_up (N=3072, K=1024)
  gemm_bt<unsigned short><<<dim3(3072 / 128, 32), 256, 0, stream>>>(
      qckvb, 1664, Wqu_t, 1024, qb, 3072, 1024);
  // rope
  {
    int total = B_ * S_ * 17 * 32;
    rope_kernel<<<(total + 255) / 256, 256, 0, stream>>>(qb, qckvb, krb, position);
  }
  // kv = ckv[:, :512] @ Wkv_up (N=4096, K=512) with fused V-transpose:
  // k_nope cols -> kvb, V cols -> vtb (transposed). Replaces pack_vt.
  gemm_kv<<<dim3(4096 / 128, 32), 256, 0, stream>>>(
      qckvb + 1024, 1664, Wkvu_t, 512, kvb, vtb, 512);
  // attention -> aob (bf16), Q-tile 128, double-buffered pipeline
  attn_mfma<<<dim3(S_ / 128, HEADS_, B_), 256, 0, stream>>>(qb, kvb, krb, vtb, aob);
  // out = aob @ Wout (fp32 out)
  gemm_bt<float><<<dim3(2048 / 128, 32), 256, 0, stream>>>(
      aob, 2048, Wout_t, 2048, out, 2048, 2048);
}